// Round 4
// baseline (12.533 us; speedup 1.0000x reference)
//
#include <hip/hip_runtime.h>

#define NB   16384
#define HID  32
#define NP   32             // per-block table resolution (31 intervals)
#define L2E  1.44269504f    // log2(e)
#define LN2  0.69314718f

// softplus via native base-2 exp/log
__device__ __forceinline__ float softplus_fast(float x) {
    return LN2 * __builtin_amdgcn_logf(1.0f + __builtin_amdgcn_exp2f(x * L2E));
}

// One kernel: each block builds a 32x32 CDF table for its axis in LDS,
// then serves 256 bilinear lookups from it.
//   blocks 0..63  -> axis 0 (var=u0, fix=u1), outputs 0..16383
//   blocks 64..127-> axis 1 (var=u1, fix=u0), outputs 16384..32767
__global__ __launch_bounds__(256) void marg_kernel(
    const float* __restrict__ U,  const float* __restrict__ W1,
    const float* __restrict__ b1, const float* __restrict__ W2,
    const float* __restrict__ b2, float* __restrict__ out)
{
    __shared__ float2 Aw[HID];       // (-L2E*w_var, -L2E*w_fix) for this block's axis
    __shared__ float2 Bp[HID];       // (softplus(W2), -L2E*b1)
    __shared__ float  b2s;
    __shared__ float  tab[NP][NP];   // tab[j_uf][i_u] = normalized CDF

    const int t    = threadIdx.x;
    const int o    = blockIdx.x * 256 + t;   // output index 0..32767
    const int axis = o >> 14;                 // block-uniform (NB = 2^14)
    const int b    = o & (NB - 1);

    // Issue the (independent) U loads immediately; latency hides under build.
    const float u  = U[axis ? NB + b : b];    // integration variable
    const float uf = U[axis ? b : NB + b];    // fixed coordinate

    if (t < HID) {
        const float spa = softplus_fast(W1[t]);        // weight of u0
        const float spb = softplus_fast(W1[HID + t]);  // weight of u1
        const float wv  = axis ? spb : spa;
        const float wf  = axis ? spa : spb;
        Aw[t] = make_float2(-L2E * wv, -L2E * wf);
        Bp[t] = make_float2(softplus_fast(W2[t]), -L2E * b1[t]);
    } else if (t == HID) {
        b2s = b2[0];
    }
    __syncthreads();

    // ---- build: 32 rows (uf) x 32 cols (x). 8 rows per pass, 4 passes. ----
    const float H   = 1.0f / (float)(NP - 1);
    const int   col = t & 31;
    const int   rw0 = t >> 5;                 // 0..7
    const float x   = (float)col * H;
    const float bb2 = b2s;

#pragma unroll
    for (int p = 0; p < 4; ++p) {
        const int   r   = rw0 + 8 * p;
        const float ufr = (float)r * H;
        float z = 0.0f;
#pragma unroll
        for (int h = 0; h < HID; ++h) {
            const float2 a  = Aw[h];
            const float2 bp = Bp[h];
            const float cc = fmaf(ufr, a.y, bp.y);
            const float tt = fmaf(x,   a.x, cc);
            z = fmaf(__builtin_amdgcn_rcpf(1.0f + __builtin_amdgcn_exp2f(tt)), bp.x, z);
        }
        const float y = softplus_fast(z + bb2);

        // trapezoid T_col over [x_{col-1}, x_col]; T_0 = 0
        const float yp = __shfl_up(y, 1, 32);
        float S = (col >= 1) ? 0.5f * H * (yp + y) : 0.0f;
        // inclusive scan over the 32-lane group
#pragma unroll
        for (int off = 1; off < 32; off <<= 1) {
            const float pr = __shfl_up(S, off, 32);
            if (col >= off) S += pr;
        }
        const float inv = 1.0f / __shfl(S, 31, 32);
        tab[r][col] = S * inv;
    }
    __syncthreads();

    // ---- lookup: bilinear in (u, uf) ----
    const float fi = u  * (float)(NP - 1);
    const float fj = uf * (float)(NP - 1);
    int i = (int)fi; i = max(0, min(i, NP - 2));
    int j = (int)fj; j = max(0, min(j, NP - 2));
    const float di = fi - (float)i;
    const float dj = fj - (float)j;

    const float f00 = tab[j][i],     f01 = tab[j][i + 1];
    const float f10 = tab[j + 1][i], f11 = tab[j + 1][i + 1];

    const float a0 = fmaf(di, f01 - f00, f00);
    const float a1 = fmaf(di, f11 - f10, f10);
    float v = fmaf(dj, a1 - a0, a0);
    v = fminf(fmaxf(v, 1e-6f), 1.0f - 1e-6f);
    out[o] = v;
}

extern "C" void kernel_launch(void* const* d_in, const int* in_sizes, int n_in,
                              void* d_out, int out_size, void* d_ws, size_t ws_size,
                              hipStream_t stream) {
    const float* U  = (const float*)d_in[0];
    const float* W1 = (const float*)d_in[1];
    const float* b1 = (const float*)d_in[2];
    const float* W2 = (const float*)d_in[3];
    const float* b2 = (const float*)d_in[4];
    float* out = (float*)d_out;

    hipLaunchKernelGGL(marg_kernel, dim3(128), dim3(256), 0, stream,
                       U, W1, b1, W2, b2, out);
}

// Round 5
// 9.493 us; speedup vs baseline: 1.3202x; 1.3202x over previous
//
#include <hip/hip_runtime.h>

#define NB   16384
#define HID  32
#define NP   32             // per-block table resolution (31 intervals)
#define L2E  1.44269504f    // log2(e)
#define LN2  0.69314718f

// softplus via native base-2 exp/log
__device__ __forceinline__ float softplus_fast(float x) {
    return LN2 * __builtin_amdgcn_logf(1.0f + __builtin_amdgcn_exp2f(x * L2E));
}

// One kernel: each block builds a 32x32 CDF table for its axis in LDS
// (4 rows per thread, INTERLEAVED through one h-loop for trans-pipe ILP),
// then serves 256 bilinear lookups from it.
__global__ __launch_bounds__(256) void marg_kernel(
    const float* __restrict__ U,  const float* __restrict__ W1,
    const float* __restrict__ b1, const float* __restrict__ W2,
    const float* __restrict__ b2, float* __restrict__ out)
{
    __shared__ float2 Aw[HID];       // (-L2E*w_var, -L2E*w_fix) for this block's axis
    __shared__ float2 Bp[HID];       // (softplus(W2), -L2E*b1)
    __shared__ float  b2s;
    __shared__ float  tab[NP][NP];   // tab[j_uf][i_u] = normalized CDF

    const int t    = threadIdx.x;
    const int o    = blockIdx.x * 256 + t;    // output index 0..32767
    const int axis = o >> 14;                 // block-uniform (NB = 2^14)
    const int b    = o & (NB - 1);

    // Issue the (independent) U loads immediately; latency hides under build.
    const float u  = U[axis ? NB + b : b];    // integration variable
    const float uf = U[axis ? b : NB + b];    // fixed coordinate

    if (t < HID) {
        const float spa = softplus_fast(W1[t]);        // weight of u0
        const float spb = softplus_fast(W1[HID + t]);  // weight of u1
        const float wv  = axis ? spb : spa;
        const float wf  = axis ? spa : spb;
        Aw[t] = make_float2(-L2E * wv, -L2E * wf);
        Bp[t] = make_float2(softplus_fast(W2[t]), -L2E * b1[t]);
    } else if (t == HID) {
        b2s = b2[0];
    }
    __syncthreads();

    // ---- build: thread owns rows {rw0, rw0+8, rw0+16, rw0+24}, col = t&31 ----
    const float H   = 1.0f / (float)(NP - 1);
    const int   col = t & 31;
    const int   rw0 = t >> 5;                 // 0..7
    const float x   = (float)col * H;
    const float uf0 = (float)(rw0     ) * H;
    const float uf1 = (float)(rw0 +  8) * H;
    const float uf2 = (float)(rw0 + 16) * H;
    const float uf3 = (float)(rw0 + 24) * H;

    float z0 = 0.0f, z1 = 0.0f, z2 = 0.0f, z3 = 0.0f;
#pragma unroll
    for (int h = 0; h < HID; ++h) {
        const float2 a  = Aw[h];
        const float2 bp = Bp[h];
        const float base = fmaf(x, a.x, bp.y);   // -L2E*(x*w_var + b1)
        const float t0 = fmaf(uf0, a.y, base);
        const float t1 = fmaf(uf1, a.y, base);
        const float t2 = fmaf(uf2, a.y, base);
        const float t3 = fmaf(uf3, a.y, base);
        const float e0 = __builtin_amdgcn_exp2f(t0);
        const float e1 = __builtin_amdgcn_exp2f(t1);
        const float e2 = __builtin_amdgcn_exp2f(t2);
        const float e3 = __builtin_amdgcn_exp2f(t3);
        z0 = fmaf(__builtin_amdgcn_rcpf(1.0f + e0), bp.x, z0);
        z1 = fmaf(__builtin_amdgcn_rcpf(1.0f + e1), bp.x, z1);
        z2 = fmaf(__builtin_amdgcn_rcpf(1.0f + e2), bp.x, z2);
        z3 = fmaf(__builtin_amdgcn_rcpf(1.0f + e3), bp.x, z3);
    }
    const float bb2 = b2s;
    float y0 = softplus_fast(z0 + bb2);
    float y1 = softplus_fast(z1 + bb2);
    float y2 = softplus_fast(z2 + bb2);
    float y3 = softplus_fast(z3 + bb2);

    // trapezoid T_col over [x_{col-1}, x_col]; T_0 = 0 (4 independent chains)
    const float c = 0.5f * H;
    float S0 = (col >= 1) ? c * (__shfl_up(y0, 1, 32) + y0) : 0.0f;
    float S1 = (col >= 1) ? c * (__shfl_up(y1, 1, 32) + y1) : 0.0f;
    float S2 = (col >= 1) ? c * (__shfl_up(y2, 1, 32) + y2) : 0.0f;
    float S3 = (col >= 1) ? c * (__shfl_up(y3, 1, 32) + y3) : 0.0f;
#pragma unroll
    for (int off = 1; off < 32; off <<= 1) {
        const float p0 = __shfl_up(S0, off, 32);
        const float p1 = __shfl_up(S1, off, 32);
        const float p2 = __shfl_up(S2, off, 32);
        const float p3 = __shfl_up(S3, off, 32);
        if (col >= off) { S0 += p0; S1 += p1; S2 += p2; S3 += p3; }
    }
    tab[rw0     ][col] = S0 * __builtin_amdgcn_rcpf(__shfl(S0, 31, 32));
    tab[rw0 +  8][col] = S1 * __builtin_amdgcn_rcpf(__shfl(S1, 31, 32));
    tab[rw0 + 16][col] = S2 * __builtin_amdgcn_rcpf(__shfl(S2, 31, 32));
    tab[rw0 + 24][col] = S3 * __builtin_amdgcn_rcpf(__shfl(S3, 31, 32));
    __syncthreads();

    // ---- lookup: bilinear in (u, uf) ----
    const float fi = u  * (float)(NP - 1);
    const float fj = uf * (float)(NP - 1);
    int i = (int)fi; i = max(0, min(i, NP - 2));
    int j = (int)fj; j = max(0, min(j, NP - 2));
    const float di = fi - (float)i;
    const float dj = fj - (float)j;

    const float f00 = tab[j][i],     f01 = tab[j][i + 1];
    const float f10 = tab[j + 1][i], f11 = tab[j + 1][i + 1];

    const float a0 = fmaf(di, f01 - f00, f00);
    const float a1 = fmaf(di, f11 - f10, f10);
    float v = fmaf(dj, a1 - a0, a0);
    v = fminf(fmaxf(v, 1e-6f), 1.0f - 1e-6f);
    out[o] = v;
}

extern "C" void kernel_launch(void* const* d_in, const int* in_sizes, int n_in,
                              void* d_out, int out_size, void* d_ws, size_t ws_size,
                              hipStream_t stream) {
    const float* U  = (const float*)d_in[0];
    const float* W1 = (const float*)d_in[1];
    const float* b1 = (const float*)d_in[2];
    const float* W2 = (const float*)d_in[3];
    const float* b2 = (const float*)d_in[4];
    float* out = (float*)d_out;

    hipLaunchKernelGGL(marg_kernel, dim3(128), dim3(256), 0, stream,
                       U, W1, b1, W2, b2, out);
}